// Round 6
// baseline (44.646 us; speedup 1.0000x reference)
//
#include <hip/hip_runtime.h>
#include <hip/hip_fp16.h>

#define FLOWS 16
#define NE 2048
#define TAB16_DWORDS (FLOWS * NE)          // 32768 dwords = 128 KB (LDS f16x2 table)
#define TAB16_BYTES  (TAB16_DWORDS * 4)
#define TAB4_BYTES   (FLOWS * NE * 16)     // 512 KB (global float4 table)
#define HYBRID_BYTES (TAB16_BYTES + TAB4_BYTES)

#define NWAVES 16
#define LDS_WAVES 9      // waves 0..8 -> LDS path, 9..15 -> L1 path
#define TROWS 8

// ---------------- MLP evaluator (table builders only) ----------------
__device__ __forceinline__ float tanh_fast(float x) {
    float e = __expf(2.0f * x);
    return 1.0f - 2.0f * __builtin_amdgcn_rcpf(e + 1.0f);
}

__device__ __forceinline__ float2 eval_mlp(int l, float z0,
        const float* __restrict__ W1, const float* __restrict__ B1,
        const float* __restrict__ W2, const float* __restrict__ B2,
        const float* __restrict__ W3, const float* __restrict__ B3,
        const float* __restrict__ W4, const float* __restrict__ B4) {
    const float* w1 = W1 + l * 10;
    const float* c1 = B1 + l * 10;
    const float* w2 = W2 + l * 100;
    const float* c2 = B2 + l * 10;
    const float* w3 = W3 + l * 200;
    const float* c3 = B3 + l * 20;
    const float* w4 = W4 + l * 40;
    const float* c4 = B4 + l * 2;

    float h1[10];
#pragma unroll
    for (int j = 0; j < 10; ++j)
        h1[j] = fmaxf(fmaf(z0, w1[j], c1[j]), 0.0f);

    float h2[10];
#pragma unroll
    for (int j = 0; j < 10; ++j) {
        float acc = c2[j];
#pragma unroll
        for (int i = 0; i < 10; ++i) acc = fmaf(h1[i], w2[i * 10 + j], acc);
        h2[j] = fmaxf(acc, 0.0f);
    }

    float h3[20];
#pragma unroll
    for (int j = 0; j < 20; ++j) {
        float acc = c3[j];
#pragma unroll
        for (int i = 0; i < 10; ++i) acc = fmaf(h2[i], w3[i * 20 + j], acc);
        h3[j] = tanh_fast(acc);
    }

    float ls = c4[0], sh = c4[1];
#pragma unroll
    for (int i = 0; i < 20; ++i) {
        ls = fmaf(h3[i], w4[i * 2 + 0], ls);
        sh = fmaf(h3[i], w4[i * 2 + 1], sh);
    }
    return make_float2(ls * 1.4426950408889634f, sh);  // (log_scale*log2e, shift)
}

// Warp: u = sign(z0)*log2(1+8|z0|); nodes u_i = -15 + i*(30/2048), i = 0..2048
__device__ __forceinline__ float node_z0(int i) {
    float u = fmaf((float)i, 30.0f / 2048.0f, -15.0f);
    float m = 0.125f * (exp2f(fabsf(u)) - 1.0f);
    return u < 0.0f ? -m : m;
}

// ---------------- merged builder: one eval/node -> f16 dword + float4 halves ----------------
// gtab16[l*2048+i]   = {ls2 f16 | sh f16<<16}           (i = 0..2047)
// tab4 [l*2048+i]    = {ls2_i, sh_i, ls2_{i+1}, sh_{i+1}} (i = 0..2047, nodes to 2048)
__global__ __launch_bounds__(256) void build_tables(
        const float* __restrict__ W1, const float* __restrict__ B1,
        const float* __restrict__ W2, const float* __restrict__ B2,
        const float* __restrict__ W3, const float* __restrict__ B3,
        const float* __restrict__ W4, const float* __restrict__ B4,
        unsigned int* __restrict__ gtab16, float2* __restrict__ tab4_as_f2) {
    int t = blockIdx.x * blockDim.x + threadIdx.x;
    if (t >= FLOWS * (NE + 1)) return;
    int l = t / (NE + 1), i = t % (NE + 1);
    float2 r = eval_mlp(l, node_z0(i), W1, B1, W2, B2, W3, B3, W4, B4);
    if (i < NE) {
        unsigned int lo = (unsigned int)__half_as_ushort(__float2half_rn(r.x));
        unsigned int hi = (unsigned int)__half_as_ushort(__float2half_rn(r.y));
        gtab16[l * NE + i] = lo | (hi << 16);
        tab4_as_f2[2 * (l * NE + i) + 0] = r;       // entry i .xy = node i
    }
    if (i > 0)
        tab4_as_f2[2 * (l * NE + i - 1) + 1] = r;   // entry i-1 .zw = node i
}

// ---------------- hybrid main kernel ----------------
__global__ __launch_bounds__(1024) void realnvp_hybrid(
        const float* __restrict__ x,
        const unsigned int* __restrict__ gtab16,
        const float4* __restrict__ tab4,
        float* __restrict__ out, int nrows) {
    __shared__ unsigned int st[TAB16_DWORDS];  // 128 KB

    // cooperative staging (all waves), 16B/lane
    {
        uint4* d = (uint4*)st;
        const uint4* s = (const uint4*)gtab16;
        for (int k = threadIdx.x; k < TAB16_DWORDS / 4; k += 1024) d[k] = s[k];
    }
    __syncthreads();

    const int wave = threadIdx.x >> 6;
    const int lane = threadIdx.x & 63;
    const int gw   = blockIdx.x * NWAVES + wave;     // global wave id
    const int rbase = gw * (TROWS * 64) + lane;      // rows: rbase + r*64

    float z0[TROWS], z1[TROWS], ld2[TROWS];
#pragma unroll
    for (int r = 0; r < TROWS; ++r) {
        const int row = rbase + r * 64;
        float2 xv = (row < nrows) ? reinterpret_cast<const float2*>(x)[row]
                                  : make_float2(0.0f, 0.0f);
        z0[r] = xv.x; z1[r] = xv.y; ld2[r] = 0.0f;
    }

    const float INV_DU = 2048.0f / 30.0f;

    if (wave < LDS_WAVES) {
        // ---- LDS path: f16x2 nodes ----
#pragma unroll 1
        for (int l = 0; l < FLOWS; ++l) {
            const unsigned int* tf = st + (l << 11);
            int idx[TROWS]; float fr[TROWS];
#pragma unroll
            for (int r = 0; r < TROWS; ++r) {
                float a  = fmaf(fabsf(z0[r]), 8.0f, 1.0f);
                float lg = __log2f(a);
                float u  = copysignf(lg, z0[r]);
                float fi = fmaf(u, INV_DU, 1024.0f);
                fi = fminf(fmaxf(fi, 0.0f), 2046.99f);
                float t = truncf(fi);
                idx[r] = (int)t;
                fr[r]  = fi - t;
            }
            unsigned int n0[TROWS], n1[TROWS];
#pragma unroll
            for (int r = 0; r < TROWS; ++r) {
                n0[r] = tf[idx[r]];
                n1[r] = tf[idx[r] + 1];
            }
#pragma unroll
            for (int r = 0; r < TROWS; ++r) {
                float ls0 = __half2float(__ushort_as_half((unsigned short)(n0[r] & 0xffffu)));
                float sh0 = __half2float(__ushort_as_half((unsigned short)(n0[r] >> 16)));
                float ls1 = __half2float(__ushort_as_half((unsigned short)(n1[r] & 0xffffu)));
                float sh1 = __half2float(__ushort_as_half((unsigned short)(n1[r] >> 16)));
                float ls2 = fmaf(fr[r], ls1 - ls0, ls0);
                float sh  = fmaf(fr[r], sh1 - sh0, sh0);
                float t   = fmaf(exp2f(ls2), z1[r], sh);
                z1[r] = z0[r]; z0[r] = t; ld2[r] += ls2;
            }
        }
    } else {
        // ---- L1 path: float4 pair entries from global ----
#pragma unroll 1
        for (int l = 0; l < FLOWS; ++l) {
            const float4* tf = tab4 + (l << 11);
            int idx[TROWS]; float fr[TROWS];
#pragma unroll
            for (int r = 0; r < TROWS; ++r) {
                float a  = fmaf(fabsf(z0[r]), 8.0f, 1.0f);
                float lg = __log2f(a);
                float u  = copysignf(lg, z0[r]);
                float fi = fmaf(u, INV_DU, 1024.0f);
                fi = fminf(fmaxf(fi, 0.0f), 2047.999f);
                float t = truncf(fi);
                idx[r] = (int)t;
                fr[r]  = fi - t;
            }
            float4 e[TROWS];
#pragma unroll
            for (int r = 0; r < TROWS; ++r) e[r] = tf[idx[r]];
#pragma unroll
            for (int r = 0; r < TROWS; ++r) {
                float ls2 = fmaf(fr[r], e[r].z - e[r].x, e[r].x);
                float sh  = fmaf(fr[r], e[r].w - e[r].y, e[r].y);
                float t   = fmaf(exp2f(ls2), z1[r], sh);
                z1[r] = z0[r]; z0[r] = t; ld2[r] += ls2;
            }
        }
    }

    float* out_lp = out;
    float2* out_z = reinterpret_cast<float2*>(out + nrows);
#pragma unroll
    for (int r = 0; r < TROWS; ++r) {
        const int row = rbase + r * 64;
        if (row < nrows) {
            const float z0n = z1[r], z1n = z0[r];
            const float ld  = ld2[r] * 0.6931471805599453f;
            const float lp  = fmaf(-0.5f, fmaf(z0n, z0n, z1n * z1n), -1.8378770664093453f) + ld;
            out_lp[row] = lp;
            out_z[row]  = make_float2(z0n, z1n);
        }
    }
}

// ---------------- fallback: LDS-only (round-5, passing) ----------------
__global__ __launch_bounds__(256) void build_table_f16(
        const float* __restrict__ W1, const float* __restrict__ B1,
        const float* __restrict__ W2, const float* __restrict__ B2,
        const float* __restrict__ W3, const float* __restrict__ B3,
        const float* __restrict__ W4, const float* __restrict__ B4,
        unsigned int* __restrict__ gtab) {
    int t = blockIdx.x * blockDim.x + threadIdx.x;
    if (t >= TAB16_DWORDS) return;
    int l = t >> 11, i = t & (NE - 1);
    float2 r = eval_mlp(l, node_z0(i), W1, B1, W2, B2, W3, B3, W4, B4);
    unsigned int lo = (unsigned int)__half_as_ushort(__float2half_rn(r.x));
    unsigned int hi = (unsigned int)__half_as_ushort(__float2half_rn(r.y));
    gtab[t] = lo | (hi << 16);
}

__global__ __launch_bounds__(1024) void realnvp_lds(
        const float* __restrict__ x,
        const unsigned int* __restrict__ gtab,
        float* __restrict__ out, int nrows) {
    __shared__ unsigned int st[TAB16_DWORDS];
    {
        uint4* d = (uint4*)st;
        const uint4* s = (const uint4*)gtab;
        for (int k = threadIdx.x; k < TAB16_DWORDS / 4; k += 1024) d[k] = s[k];
    }
    __syncthreads();

    const int rbase = blockIdx.x * (TROWS * 1024) + threadIdx.x;
    float z0[TROWS], z1[TROWS], ld2[TROWS];
#pragma unroll
    for (int r = 0; r < TROWS; ++r) {
        const int row = rbase + r * 1024;
        float2 xv = (row < nrows) ? reinterpret_cast<const float2*>(x)[row]
                                  : make_float2(0.0f, 0.0f);
        z0[r] = xv.x; z1[r] = xv.y; ld2[r] = 0.0f;
    }
    const float INV_DU = 2048.0f / 30.0f;
#pragma unroll 1
    for (int l = 0; l < FLOWS; ++l) {
        const unsigned int* tf = st + (l << 11);
        int idx[TROWS]; float fr[TROWS];
#pragma unroll
        for (int r = 0; r < TROWS; ++r) {
            float a  = fmaf(fabsf(z0[r]), 8.0f, 1.0f);
            float lg = __log2f(a);
            float u  = copysignf(lg, z0[r]);
            float fi = fmaf(u, INV_DU, 1024.0f);
            fi = fminf(fmaxf(fi, 0.0f), 2046.99f);
            float t = truncf(fi);
            idx[r] = (int)t; fr[r] = fi - t;
        }
        unsigned int n0[TROWS], n1[TROWS];
#pragma unroll
        for (int r = 0; r < TROWS; ++r) { n0[r] = tf[idx[r]]; n1[r] = tf[idx[r] + 1]; }
#pragma unroll
        for (int r = 0; r < TROWS; ++r) {
            float ls0 = __half2float(__ushort_as_half((unsigned short)(n0[r] & 0xffffu)));
            float sh0 = __half2float(__ushort_as_half((unsigned short)(n0[r] >> 16)));
            float ls1 = __half2float(__ushort_as_half((unsigned short)(n1[r] & 0xffffu)));
            float sh1 = __half2float(__ushort_as_half((unsigned short)(n1[r] >> 16)));
            float ls2 = fmaf(fr[r], ls1 - ls0, ls0);
            float sh  = fmaf(fr[r], sh1 - sh0, sh0);
            float t   = fmaf(exp2f(ls2), z1[r], sh);
            z1[r] = z0[r]; z0[r] = t; ld2[r] += ls2;
        }
    }
    float* out_lp = out;
    float2* out_z = reinterpret_cast<float2*>(out + nrows);
#pragma unroll
    for (int r = 0; r < TROWS; ++r) {
        const int row = rbase + r * 1024;
        if (row < nrows) {
            const float z0n = z1[r], z1n = z0[r];
            const float ld  = ld2[r] * 0.6931471805599453f;
            const float lp  = fmaf(-0.5f, fmaf(z0n, z0n, z1n * z1n), -1.8378770664093453f) + ld;
            out_lp[row] = lp;
            out_z[row]  = make_float2(z0n, z1n);
        }
    }
}

// ---------------- launcher ----------------
extern "C" void kernel_launch(void* const* d_in, const int* in_sizes, int n_in,
                              void* d_out, int out_size, void* d_ws, size_t ws_size,
                              hipStream_t stream) {
    const float* x  = (const float*)d_in[0];
    const float* W1 = (const float*)d_in[1];
    const float* B1 = (const float*)d_in[2];
    const float* W2 = (const float*)d_in[3];
    const float* B2 = (const float*)d_in[4];
    const float* W3 = (const float*)d_in[5];
    const float* B3 = (const float*)d_in[6];
    const float* W4 = (const float*)d_in[7];
    const float* B4 = (const float*)d_in[8];
    const int nrows = in_sizes[0] / 2;

    if (ws_size >= (size_t)HYBRID_BYTES) {
        unsigned int* gtab16 = (unsigned int*)d_ws;
        float4* tab4 = (float4*)((char*)d_ws + TAB16_BYTES);
        const int nb = (FLOWS * (NE + 1) + 255) / 256;
        build_tables<<<nb, 256, 0, stream>>>(W1, B1, W2, B2, W3, B3, W4, B4,
                                             gtab16, (float2*)tab4);
        const int rows_per_block = NWAVES * TROWS * 64;  // 8192
        const int blocks = (nrows + rows_per_block - 1) / rows_per_block;
        realnvp_hybrid<<<blocks, 1024, 0, stream>>>(x, gtab16, tab4, (float*)d_out, nrows);
    } else if (ws_size >= (size_t)TAB16_BYTES) {
        unsigned int* gtab = (unsigned int*)d_ws;
        build_table_f16<<<(TAB16_DWORDS + 255) / 256, 256, 0, stream>>>(
            W1, B1, W2, B2, W3, B3, W4, B4, gtab);
        const int rows_per_block = TROWS * 1024;
        const int blocks = (nrows + rows_per_block - 1) / rows_per_block;
        realnvp_lds<<<blocks, 1024, 0, stream>>>(x, gtab, (float*)d_out, nrows);
    }
}

// Round 8
// 37.817 us; speedup vs baseline: 1.1806x; 1.1806x over previous
//
#include <hip/hip_runtime.h>
#include <hip/hip_fp16.h>

#define FLOWS 16
#define NE 1024                       // interp intervals per flow
#define TAB_QWORDS (FLOWS * NE)       // 16384 x 8B = 128 KB
#define TAB_BYTES  (TAB_QWORDS * 8)

#define TROWS 8
#define BLOCK 1024

// ---------------- MLP evaluator (table builder only) ----------------
__device__ __forceinline__ float tanh_fast(float x) {
    float e = __expf(2.0f * x);
    return 1.0f - 2.0f * __builtin_amdgcn_rcpf(e + 1.0f);
}

__device__ __forceinline__ float2 eval_mlp(int l, float z0,
        const float* __restrict__ W1, const float* __restrict__ B1,
        const float* __restrict__ W2, const float* __restrict__ B2,
        const float* __restrict__ W3, const float* __restrict__ B3,
        const float* __restrict__ W4, const float* __restrict__ B4) {
    const float* w1 = W1 + l * 10;
    const float* c1 = B1 + l * 10;
    const float* w2 = W2 + l * 100;
    const float* c2 = B2 + l * 10;
    const float* w3 = W3 + l * 200;
    const float* c3 = B3 + l * 20;
    const float* w4 = W4 + l * 40;
    const float* c4 = B4 + l * 2;

    float h1[10];
#pragma unroll
    for (int j = 0; j < 10; ++j)
        h1[j] = fmaxf(fmaf(z0, w1[j], c1[j]), 0.0f);

    float h2[10];
#pragma unroll
    for (int j = 0; j < 10; ++j) {
        float acc = c2[j];
#pragma unroll
        for (int i = 0; i < 10; ++i) acc = fmaf(h1[i], w2[i * 10 + j], acc);
        h2[j] = fmaxf(acc, 0.0f);
    }

    float h3[20];
#pragma unroll
    for (int j = 0; j < 20; ++j) {
        float acc = c3[j];
#pragma unroll
        for (int i = 0; i < 10; ++i) acc = fmaf(h2[i], w3[i * 20 + j], acc);
        h3[j] = tanh_fast(acc);
    }

    float ls = c4[0], sh = c4[1];
#pragma unroll
    for (int i = 0; i < 20; ++i) {
        ls = fmaf(h3[i], w4[i * 2 + 0], ls);
        sh = fmaf(h3[i], w4[i * 2 + 1], sh);
    }
    return make_float2(ls * 1.4426950408889634f, sh);  // (log_scale*log2e, shift)
}

// Warp: u = sign(z0)*log2(1+8|z0|); nodes u_i = -15 + i*(30/1024), i = 0..1024
__device__ __forceinline__ float node_z0(int i) {
    float u = fmaf((float)i, 30.0f / 1024.0f, -15.0f);
    float m = 0.125f * (exp2f(fabsf(u)) - 1.0f);
    return u < 0.0f ? -m : m;
}

__device__ __forceinline__ unsigned int pack_h2(float a, float b) {
    unsigned int lo = (unsigned int)__half_as_ushort(__float2half_rn(a));
    unsigned int hi = (unsigned int)__half_as_ushort(__float2half_rn(b));
    return lo | (hi << 16);
}

// entry i: .x = {f16 ls2_i | f16 sh_i}, .y = {f16 (ls2_{i+1}-ls2_i) | f16 (sh_{i+1}-sh_i)}
// deltas are computed on the f16-rounded node values so fr=1 reproduces node i+1 exactly.
__global__ __launch_bounds__(256) void build_table_d(
        const float* __restrict__ W1, const float* __restrict__ B1,
        const float* __restrict__ W2, const float* __restrict__ B2,
        const float* __restrict__ W3, const float* __restrict__ B3,
        const float* __restrict__ W4, const float* __restrict__ B4,
        uint2* __restrict__ gtab) {
    int t = blockIdx.x * blockDim.x + threadIdx.x;
    if (t >= TAB_QWORDS) return;
    int l = t >> 10, i = t & (NE - 1);
    float2 r0 = eval_mlp(l, node_z0(i),     W1, B1, W2, B2, W3, B3, W4, B4);
    float2 r1 = eval_mlp(l, node_z0(i + 1), W1, B1, W2, B2, W3, B3, W4, B4);
    // round nodes to f16 first, then difference (in f32, re-rounded to f16)
    float ls0 = __half2float(__float2half_rn(r0.x));
    float sh0 = __half2float(__float2half_rn(r0.y));
    float ls1 = __half2float(__float2half_rn(r1.x));
    float sh1 = __half2float(__float2half_rn(r1.y));
    uint2 e;
    e.x = pack_h2(ls0, sh0);
    e.y = pack_h2(ls1 - ls0, sh1 - sh0);
    gtab[t] = e;
}

// ---------------- main kernel ----------------
typedef __fp16 pkrtz_t __attribute__((ext_vector_type(2)));  // native return type of cvt_pkrtz

__global__ __launch_bounds__(BLOCK) void realnvp_lds64(
        const float* __restrict__ x,
        const uint2* __restrict__ gtab,
        float* __restrict__ out, int nrows) {
    __shared__ uint2 st[TAB_QWORDS];  // 128 KB

    // stage table: 16 B/lane coalesced
    {
        uint4* d = (uint4*)st;
        const uint4* s = (const uint4*)gtab;
        for (int k = threadIdx.x; k < TAB_QWORDS / 2; k += BLOCK) d[k] = s[k];
    }
    __syncthreads();

    const int rbase = blockIdx.x * (TROWS * BLOCK) + threadIdx.x;

    float z0[TROWS], z1[TROWS], ld2[TROWS];
#pragma unroll
    for (int r = 0; r < TROWS; ++r) {
        const int row = rbase + r * BLOCK;
        float2 xv = (row < nrows) ? reinterpret_cast<const float2*>(x)[row]
                                  : make_float2(0.0f, 0.0f);
        z0[r] = xv.x; z1[r] = xv.y; ld2[r] = 0.0f;
    }

    const float INV_DU = 1024.0f / 30.0f;

#pragma unroll 1
    for (int l = 0; l < FLOWS; ++l) {
        const uint2* tf = st + (l << 10);

        int idx[TROWS]; float fr[TROWS];
#pragma unroll
        for (int r = 0; r < TROWS; ++r) {
            float a  = fmaf(fabsf(z0[r]), 8.0f, 1.0f);   // 1 + |z0|/0.125
            float lg = __log2f(a);
            float u  = copysignf(lg, z0[r]);
            float fi = fmaf(u, INV_DU, 512.0f);
            fi = fminf(fmaxf(fi, 0.0f), 1023.99f);
            float t = truncf(fi);
            idx[r] = (int)t;
            fr[r]  = fi - t;
        }

        uint2 e[TROWS];
#pragma unroll
        for (int r = 0; r < TROWS; ++r)
            e[r] = tf[idx[r]];                           // one ds_read_b64 each

#pragma unroll
        for (int r = 0; r < TROWS; ++r) {
            // v = base + fr * delta, packed f16
            pkrtz_t fr2 = __builtin_amdgcn_cvt_pkrtz(fr[r], fr[r]);  // v_cvt_pkrtz
            __half2 frh, base, del;
            __builtin_memcpy(&frh,  &fr2,    4);
            __builtin_memcpy(&base, &e[r].x, 4);
            __builtin_memcpy(&del,  &e[r].y, 4);
            __half2 v = __hfma2(frh, del, base);         // v_pk_fma_f16
            float ls2 = __half2float(__low2half(v));
            float sh  = __half2float(__high2half(v));
            float t   = fmaf(exp2f(ls2), z1[r], sh);
            z1[r] = z0[r];
            z0[r] = t;
            ld2[r] += ls2;
        }
    }

    float* out_lp = out;
    float2* out_z = reinterpret_cast<float2*>(out + nrows);
#pragma unroll
    for (int r = 0; r < TROWS; ++r) {
        const int row = rbase + r * BLOCK;
        if (row < nrows) {
            const float z0n = z1[r], z1n = z0[r];
            const float ld  = ld2[r] * 0.6931471805599453f;
            const float lp  = fmaf(-0.5f, fmaf(z0n, z0n, z1n * z1n), -1.8378770664093453f) + ld;
            out_lp[row] = lp;
            out_z[row]  = make_float2(z0n, z1n);
        }
    }
}

// ---------------- launcher ----------------
extern "C" void kernel_launch(void* const* d_in, const int* in_sizes, int n_in,
                              void* d_out, int out_size, void* d_ws, size_t ws_size,
                              hipStream_t stream) {
    const float* x  = (const float*)d_in[0];
    const float* W1 = (const float*)d_in[1];
    const float* B1 = (const float*)d_in[2];
    const float* W2 = (const float*)d_in[3];
    const float* B2 = (const float*)d_in[4];
    const float* W3 = (const float*)d_in[5];
    const float* B3 = (const float*)d_in[6];
    const float* W4 = (const float*)d_in[7];
    const float* B4 = (const float*)d_in[8];
    const int nrows = in_sizes[0] / 2;

    uint2* gtab = (uint2*)d_ws;  // needs 128 KB; ws is far larger (validated rounds 4-6)
    build_table_d<<<(TAB_QWORDS + 255) / 256, 256, 0, stream>>>(
        W1, B1, W2, B2, W3, B3, W4, B4, gtab);

    const int rows_per_block = TROWS * BLOCK;  // 8192
    const int blocks = (nrows + rows_per_block - 1) / rows_per_block;
    realnvp_lds64<<<blocks, BLOCK, 0, stream>>>(x, gtab, (float*)d_out, nrows);
}